// Round 4
// baseline (198.077 us; speedup 1.0000x reference)
//
#include <hip/hip_runtime.h>
#include <hip/hip_bf16.h>
#include <math.h>

// Problem constants: B=2, T=2048, C=1024, H=16, D=64
#define BB 2
#define TT 2048
#define HH 16
#define DD 64
#define CC 1024
#define C3 3072

typedef __attribute__((ext_vector_type(8))) short bf16x8;
typedef __attribute__((ext_vector_type(4))) short bf16x4;
typedef __attribute__((ext_vector_type(4))) float f32x4;
typedef __attribute__((ext_vector_type(2))) unsigned int u32x2;

// round-to-nearest-even fp32 -> bf16 bits
__device__ __forceinline__ unsigned short f2bf(float f) {
  union { float f; unsigned u; } v; v.f = f;
  unsigned r = v.u + 0x7fffu + ((v.u >> 16) & 1u);
  return (unsigned short)(r >> 16);
}
// packed 2x fp32 -> bf16x2 (v_cvt_pk_bf16_f32 on gfx950), RNE
__device__ __forceinline__ unsigned pack2bf(float a, float b) {
  __hip_bfloat162 h = __float22bfloat162_rn(make_float2(a, b));
  union { __hip_bfloat162 h; unsigned u; } cv; cv.h = h;
  return cv.u;
}

// async global->LDS 16B copy (dest = wave-uniform base + lane*16)
__device__ __forceinline__ void async_cp16(const void* g, void* l) {
  __builtin_amdgcn_global_load_lds(
      (const __attribute__((address_space(1))) void*)g,
      (__attribute__((address_space(3))) void*)l, 16, 0, 0);
}

// ---------------------------------------------------------------------------
// prep: one launch does x->bf16 cvt + both weight transposes.
// ---------------------------------------------------------------------------
__global__ __launch_bounds__(256)
void prep(const float* __restrict__ x, const float* __restrict__ w_attn,
          const float* __restrict__ w_proj, unsigned short* __restrict__ xb,
          unsigned short* __restrict__ wat, unsigned short* __restrict__ wpt) {
  __shared__ __align__(16) float Ts[64][68];
  const int bx = blockIdx.x, tid = threadIdx.x;
  if (bx < 1024) {
    int i = bx * 256 + tid;
#pragma unroll
    for (int it = 0; it < 4; ++it, i += 262144) {
      const float4 v = ((const float4*)x)[i];
      bf16x4 o = {(short)f2bf(v.x), (short)f2bf(v.y),
                  (short)f2bf(v.z), (short)f2bf(v.w)};
      ((bf16x4*)xb)[i] = o;
    }
    return;
  }
  const float* W;
  unsigned short* WT;
  int Nd, bound, n0, k0;
  float s;
  if (bx < 1792) {
    const int bid = bx - 1024;
    W = w_attn; WT = wat; Nd = 3072; bound = 1024; s = 0.18033688f;  // 0.125*log2e
    n0 = (bid % 48) * 64; k0 = (bid / 48) * 64;
  } else {
    const int bid = bx - 1792;
    W = w_proj; WT = wpt; Nd = 1024; bound = 0; s = 1.0f;
    n0 = (bid % 16) * 64; k0 = (bid / 16) * 64;
  }
  const int rl = tid >> 4, c4 = tid & 15;
#pragma unroll
  for (int it = 0; it < 4; ++it) {
    const int r = it * 16 + rl;
    *(float4*)&Ts[r][c4 * 4] =
        *(const float4*)(W + (size_t)(k0 + r) * Nd + n0 + c4 * 4);
  }
  __syncthreads();
#pragma unroll
  for (int it = 0; it < 4; ++it) {
    const int n = it * 16 + rl;
    const float sc = (n0 + n < bound) ? s : 1.0f;
    bf16x4 o = {(short)f2bf(Ts[c4 * 4 + 0][n] * sc),
                (short)f2bf(Ts[c4 * 4 + 1][n] * sc),
                (short)f2bf(Ts[c4 * 4 + 2][n] * sc),
                (short)f2bf(Ts[c4 * 4 + 3][n] * sc)};
    *(bf16x4*)(WT + (size_t)(n0 + n) * CC + k0 + c4 * 4) = o;
  }
}

// ---------------------------------------------------------------------------
// gemm_qkv: qkv = xb(4096x1024) @ wat(3072x1024)^T.  Tile 128x128, BK=32,
// dbuf LDS (32 KB), grid 24x32 = 768 blocks = 3 blocks/CU.
// bf16 out; cols>=2048 (V) written transposed into vt[(b*16+h)*64+d][t].
// ---------------------------------------------------------------------------
__global__ __launch_bounds__(256, 3)
void gemm_qkv(const unsigned short* __restrict__ A,
              const unsigned short* __restrict__ BT,
              unsigned short* __restrict__ Cb,
              unsigned short* __restrict__ Vout) {
  __shared__ __align__(16) unsigned short As[2 * 128 * 32];  // 16 KB
  __shared__ __align__(16) unsigned short Bs[2 * 128 * 32];  // 16 KB

  const int tid = threadIdx.x;
  const int w = tid >> 6, lane = tid & 63;
  const int l15 = lane & 15, quad = lane >> 4;
  const int wm = w >> 1, wn = w & 1;
  const int row0 = blockIdx.y * 128, col0 = blockIdx.x * 128;

  const int ca0 = tid, ca1 = tid + 256;
  const int ra0 = ca0 >> 2, ka0 = ((ca0 & 3) ^ ((ca0 >> 3) & 3)) * 8;
  const int ra1 = ca1 >> 2, ka1 = ((ca1 & 3) ^ ((ca1 >> 3) & 3)) * 8;
  const unsigned short* gA0 = A + (size_t)(row0 + ra0) * CC + ka0;
  const unsigned short* gA1 = A + (size_t)(row0 + ra1) * CC + ka1;
  const unsigned short* gB0 = BT + (size_t)(col0 + ra0) * CC + ka0;
  const unsigned short* gB1 = BT + (size_t)(col0 + ra1) * CC + ka1;
  const int la0 = tid * 16, la1 = tid * 16 + 4096;

  const int fro = l15 * 64 + 16 * (quad ^ ((l15 >> 1) & 3));

  f32x4 acc[4][4];
#pragma unroll
  for (int i = 0; i < 4; ++i)
#pragma unroll
    for (int j = 0; j < 4; ++j) acc[i][j] = (f32x4){0.f, 0.f, 0.f, 0.f};

  async_cp16(gA0, (char*)As + la0);
  async_cp16(gA1, (char*)As + la1);
  async_cp16(gB0, (char*)Bs + la0);
  async_cp16(gB1, (char*)Bs + la1);

  for (int i = 0; i < 32; ++i) {
    const int cur = i & 1;
    __syncthreads();

    if (i + 1 < 32) {
      const int k1 = (i + 1) * 32;
      const int ab = (cur ^ 1) * 8192;
      async_cp16(gA0 + k1, (char*)As + ab + la0);
      async_cp16(gA1 + k1, (char*)As + ab + la1);
      async_cp16(gB0 + k1, (char*)Bs + ab + la0);
      async_cp16(gB1 + k1, (char*)Bs + ab + la1);
    }

    const char* fA = (const char*)As + cur * 8192 + wm * 4096 + fro;
    const char* fB = (const char*)Bs + cur * 8192 + wn * 4096 + fro;

    bf16x8 af[4], bf[4];
#pragma unroll
    for (int mt = 0; mt < 4; ++mt) af[mt] = *(const bf16x8*)(fA + mt * 1024);
#pragma unroll
    for (int nt = 0; nt < 4; ++nt) bf[nt] = *(const bf16x8*)(fB + nt * 1024);
#pragma unroll
    for (int mt = 0; mt < 4; ++mt)
#pragma unroll
      for (int nt = 0; nt < 4; ++nt)
        acc[mt][nt] = __builtin_amdgcn_mfma_f32_16x16x32_bf16(
            af[mt], bf[nt], acc[mt][nt], 0, 0, 0);
  }

  if (col0 >= 2048) {
#pragma unroll
    for (int mt = 0; mt < 4; ++mt) {
      const int rbase = row0 + wm * 64 + mt * 16 + quad * 4;
      const int bq = rbase >> 11, t0 = rbase & 2047;
#pragma unroll
      for (int nt = 0; nt < 4; ++nt) {
        const int d = col0 + wn * 64 + nt * 16 + l15 - 2048;
        bf16x4 o = {(short)f2bf(acc[mt][nt][0]), (short)f2bf(acc[mt][nt][1]),
                    (short)f2bf(acc[mt][nt][2]), (short)f2bf(acc[mt][nt][3])};
        *(bf16x4*)(Vout + (((size_t)(bq << 10) + d) << 11) + t0) = o;
      }
    }
  } else {
#pragma unroll
    for (int mt = 0; mt < 4; ++mt) {
      const int rbase = row0 + wm * 64 + mt * 16 + quad * 4;
#pragma unroll
      for (int r = 0; r < 4; ++r) {
        unsigned short* cr =
            Cb + (size_t)(rbase + r) * C3 + col0 + wn * 64 + l15;
#pragma unroll
        for (int nt = 0; nt < 4; ++nt) cr[nt * 16] = f2bf(acc[mt][nt][r]);
      }
    }
  }
}

// ---------------------------------------------------------------------------
// gemm_out: out(4096x1024 fp32) = yb(4096x1024) @ wpt(1024x1024)^T.
// ---------------------------------------------------------------------------
__global__ __launch_bounds__(256, 2)
void gemm_out(const unsigned short* __restrict__ A,
              const unsigned short* __restrict__ BT,
              float* __restrict__ Cf) {
  __shared__ __align__(16) unsigned short As[2 * 64 * 64];    // 16 KB
  __shared__ __align__(16) unsigned short Bs[2 * 128 * 64];   // 32 KB

  const int tid = threadIdx.x;
  const int w = tid >> 6, lane = tid & 63;
  const int l15 = lane & 15, quad = lane >> 4;
  const int wm = w >> 1, wn = w & 1;
  const int row0 = blockIdx.y * 64, col0 = blockIdx.x * 128;

  const int ca0 = tid, ca1 = tid + 256;
  const int ra0 = ca0 >> 3, ka0 = ((ca0 & 7) ^ ((ca0 >> 3) & 7)) * 8;
  const int ra1 = ca1 >> 3, ka1 = ((ca1 & 7) ^ ((ca1 >> 3) & 7)) * 8;
  const unsigned short* gA0 = A + (size_t)(row0 + ra0) * CC + ka0;
  const unsigned short* gA1 = A + (size_t)(row0 + ra1) * CC + ka1;
  const unsigned short* gB[4];
  int lb[4];
#pragma unroll
  for (int t = 0; t < 4; ++t) {
    const int c = tid + t * 256;
    const int rb = c >> 3, kb = ((c & 7) ^ ((c >> 3) & 7)) * 8;
    gB[t] = BT + (size_t)(col0 + rb) * CC + kb;
    lb[t] = c * 16;
  }
  const int la0 = tid * 16, la1 = tid * 16 + 4096;

  const int fro = l15 * 128 + ((quad ^ (l15 & 7)) << 4);

  f32x4 acc[2][4];
#pragma unroll
  for (int i = 0; i < 2; ++i)
#pragma unroll
    for (int j = 0; j < 4; ++j) acc[i][j] = (f32x4){0.f, 0.f, 0.f, 0.f};

  async_cp16(gA0, (char*)As + la0);
  async_cp16(gA1, (char*)As + la1);
#pragma unroll
  for (int t = 0; t < 4; ++t) async_cp16(gB[t], (char*)Bs + lb[t]);

  for (int i = 0; i < 16; ++i) {
    const int cur = i & 1;
    __syncthreads();

    if (i + 1 < 16) {
      const int k1 = (i + 1) * 64;
      const int ab = (cur ^ 1) * 8192, bb = (cur ^ 1) * 16384;
      async_cp16(gA0 + k1, (char*)As + ab + la0);
      async_cp16(gA1 + k1, (char*)As + ab + la1);
#pragma unroll
      for (int t = 0; t < 4; ++t) async_cp16(gB[t] + k1, (char*)Bs + bb + lb[t]);
    }

    const char* fA = (const char*)As + cur * 8192 + wm * 4096 + fro;
    const char* fB = (const char*)Bs + cur * 16384 + wn * 8192 + fro;

#pragma unroll
    for (int kh = 0; kh < 2; ++kh) {
      const int xo = kh * 64;
      bf16x8 af[2], bf[4];
#pragma unroll
      for (int mt = 0; mt < 2; ++mt)
        af[mt] = *(const bf16x8*)(fA + mt * 2048 + ((fro + xo) & 127) - (fro & 127));
#pragma unroll
      for (int nt = 0; nt < 4; ++nt)
        bf[nt] = *(const bf16x8*)(fB + nt * 2048 + ((fro + xo) & 127) - (fro & 127));
#pragma unroll
      for (int mt = 0; mt < 2; ++mt)
#pragma unroll
        for (int nt = 0; nt < 4; ++nt)
          acc[mt][nt] = __builtin_amdgcn_mfma_f32_16x16x32_bf16(
              af[mt], bf[nt], acc[mt][nt], 0, 0, 0);
    }
  }

#pragma unroll
  for (int mt = 0; mt < 2; ++mt) {
    const int rbase = row0 + wm * 32 + mt * 16 + quad * 4;
#pragma unroll
    for (int r = 0; r < 4; ++r) {
      float* cr = Cf + (size_t)(rbase + r) * CC + col0 + wn * 64 + l15;
#pragma unroll
      for (int nt = 0; nt < 4; ++nt) cr[nt * 16] = acc[mt][nt][r];
    }
  }
}

// ---------------------------------------------------------------------------
// MFMA flash attention, round-15: 2x2 HYBRID wave split (q-half x key-parity).
// r3 post-mortem: "one wave owns all 64 q" needs qf32+O64 -> spills at any
// occupancy target >2 waves/SIMD.  Hybrid halves both: wave w owns q-half
// (w>>1, 32 rows) and key chunks c = (w&1), (w&1)+2, ...  State: qf 16 +
// O 32 + kf 16 + vf 16 + ~25 transient = ~110-125 regs -> 3-4 waves/SIMD,
// NO spill.  Same total MFMA count.
//  * grid 1024 (one 64-row q-tile per block) = exactly 4 blocks/CU, all
//    resident; per-CU balanced qt mapping {p, 31-p, 15-p, 16+p}.
//  * K/V frags direct from L2 (2x redundant across q-halves; L2-resident).
//  * P staged per-wave-private (ct-XOR swizzle), 4.6 KB/wave = 18.4 KB.
//  * epilogue: single pair-exchange (w0+=w1 | w2+=w3, parallel), 2 barriers;
//    Red aliased over Ps arena.  l-sum on VALU from bf16-rounded P (r3,
//    verified numerics), quad-reduced by shfl_xor.
// ---------------------------------------------------------------------------
__device__ __forceinline__ void s_exp_store2(
    const int c, const int qt, const int qh, const int l15, const int quad,
    const bf16x8 (&kf)[2][2], const bf16x8 (&qf)[2][2],
    char* psw, const int psrow, float (&lsum)[2]) {
#pragma unroll
  for (int ks = 0; ks < 2; ++ks)
#pragma unroll
    for (int qs = 0; qs < 2; ++qs) {
      f32x4 z = (f32x4){-12.f, -12.f, -12.f, -12.f};
      z = __builtin_amdgcn_mfma_f32_16x16x32_bf16(kf[ks][0], qf[qs][0], z, 0, 0, 0);
      z = __builtin_amdgcn_mfma_f32_16x16x32_bf16(kf[ks][1], qf[qs][1], z, 0, 0, 0);
      if (c >= 2 * qt + qh) {  // only the wave's last chunk can be diagonal
#pragma unroll
        for (int r = 0; r < 4; ++r)
          if (32 * c + ks * 16 + quad * 4 + r >
              qt * 64 + qh * 32 + qs * 16 + l15)
            z[r] = -INFINITY;
      }
      u32x2 d;
      d[0] = pack2bf(__builtin_amdgcn_exp2f(z[0]),
                     __builtin_amdgcn_exp2f(z[1]));
      d[1] = pack2bf(__builtin_amdgcn_exp2f(z[2]),
                     __builtin_amdgcn_exp2f(z[3]));
      // l-sum of the bf16-ROUNDED values (verified in r3)
      lsum[qs] += __uint_as_float(d[0] << 16) +
                  __uint_as_float(d[0] & 0xffff0000u) +
                  __uint_as_float(d[1] << 16) +
                  __uint_as_float(d[1] & 0xffff0000u);
      *(u32x2*)(psw + qs * 2304 + psrow + (((ks + l15) & 3) << 5) + quad * 8) = d;
    }
}

__device__ __forceinline__ void pv_accum2(
    const int l15, const int quad, const bf16x8 (&vf)[4],
    const char* psw, const int psrow, f32x4 (&O)[4][2]) {
  __builtin_amdgcn_s_setprio(1);
#pragma unroll
  for (int qs = 0; qs < 2; ++qs) {
    const bf16x8 pf = *(const bf16x8*)(psw + qs * 2304 + psrow +
                                       ((((quad >> 1) + l15) & 3) << 5) +
                                       ((quad & 1) << 4));
#pragma unroll
    for (int dt = 0; dt < 4; ++dt)
      O[dt][qs] = __builtin_amdgcn_mfma_f32_16x16x32_bf16(vf[dt], pf, O[dt][qs], 0, 0, 0);
  }
  __builtin_amdgcn_s_setprio(0);
}

#define LOADK_P(dst, kp)                                                 \
  do {                                                                   \
    dst[0][0] = *(const bf16x8*)(kp);                                    \
    dst[0][1] = *(const bf16x8*)((kp) + 32);                             \
    dst[1][0] = *(const bf16x8*)((kp) + 16 * C3);                        \
    dst[1][1] = *(const bf16x8*)((kp) + 16 * C3 + 32);                   \
  } while (0)

#define LOADV_P(dst, vp)                                                 \
  do {                                                                   \
    dst[0] = *(const bf16x8*)(vp);                                       \
    dst[1] = *(const bf16x8*)((vp) + 16 * TT);                           \
    dst[2] = *(const bf16x8*)((vp) + 32 * TT);                           \
    dst[3] = *(const bf16x8*)((vp) + 48 * TT);                           \
  } while (0)

__global__ __launch_bounds__(256, 3)
void attn_mfma(const unsigned short* __restrict__ qkvb,
               const unsigned short* __restrict__ vt,
               unsigned short* __restrict__ y) {
  const int n = blockIdx.x;
  const int bh = (n & 7) + 8 * ((n >> 3) & 3);  // 4 bh per XCD -> 2MB L2 set
  const int m = n >> 5, p = m & 7, g = m >> 3;
  // per-CU balanced qt: CU sees {p, 31-p, 15-p, 16+p} (sum 62+2p-... const 62)
  const int qt = (g == 0) ? p : (g == 1) ? 31 - p : (g == 2) ? 15 - p : 16 + p;
  const int b = bh >> 4, h = bh & 15;
  const int tid = threadIdx.x;
  const int w = tid >> 6, lane = tid & 63;
  const int l15 = lane & 15, quad = lane >> 4;
  const int qh = w >> 1, kp2 = w & 1;

  __shared__ __align__(16) char arena[18432];  // Ps (main) / Red (epilogue)
  __shared__ float Red2[2][2][16];

  char* psw = arena + w * 4608;  // per-wave private P staging (ct-XOR swz)
  const int psrow = l15 * 144;
  const int epoff = l15 * 64 + ((quad ^ (l15 & 3)) << 4);

  // K frag: A[m=key16][k=d32]; lane key = 32c + ks*16 + l15, d = kh*32+quad*8
  const unsigned short* kbase =
      qkvb + (size_t)(b * TT + l15) * C3 + 1024 + h * DD + quad * 8;
  // V frag: vt row d = bh*64 + dt*16 + l15, t = 32c + quad*8
  const unsigned short* vbase =
      vt + (size_t)(bh * DD + l15) * TT + quad * 8;

  // Q fragments: this wave's 32 rows (pre-scaled by 0.125*log2e in prep)
  const unsigned short* qbase =
      qkvb + (size_t)(b * TT + qt * 64 + qh * 32 + l15) * C3 + h * DD + quad * 8;
  bf16x8 qf[2][2];
#pragma unroll
  for (int qs = 0; qs < 2; ++qs)
#pragma unroll
    for (int kh = 0; kh < 2; ++kh)
      qf[qs][kh] = *(const bf16x8*)(qbase + qs * 16 * C3 + kh * 32);

  f32x4 O[4][2];
  float lsum[2] = {0.f, 0.f};
#pragma unroll
  for (int dt = 0; dt < 4; ++dt)
#pragma unroll
    for (int qs = 0; qs < 2; ++qs) O[dt][qs] = (f32x4){0.f, 0.f, 0.f, 0.f};

  // ---- barrier-free main loop: wave owns chunks kp2, kp2+2, ... <= cl ----
  const int cl = 2 * qt + qh;  // last chunk this q-half can see
  int c = kp2;
  if (c <= cl) {
    const unsigned short* kp = kbase + (size_t)(32 * c) * C3;
    const unsigned short* vp = vbase + 32 * c;
    bf16x8 kf[2][2], vf[4];
    LOADK_P(kf, kp);
    LOADV_P(vf, vp);
    while (c + 2 <= cl) {  // steady state: unconditional reloads
      s_exp_store2(c, qt, qh, l15, quad, kf, qf, psw, psrow, lsum);
      kp += (size_t)64 * C3;
      LOADK_P(kf, kp);                       // next chunk's K (reuse regs)
      pv_accum2(l15, quad, vf, psw, psrow, O);
      vp += 64;
      LOADV_P(vf, vp);                       // next chunk's V (reuse regs)
      c += 2;
    }
    // last chunk (no prefetch)
    s_exp_store2(c, qt, qh, l15, quad, kf, qf, psw, psrow, lsum);
    pv_accum2(l15, quad, vf, psw, psrow, O);
  }

  // ---- intra-wave l reduce across quads ----
#pragma unroll
  for (int qs = 0; qs < 2; ++qs) {
    lsum[qs] += __shfl_xor(lsum[qs], 16, 64);
    lsum[qs] += __shfl_xor(lsum[qs], 32, 64);
  }

  // ---- pair-exchange over key-parity: w0+=w1 and w2+=w3 (parallel) ----
  __syncthreads();  // all Ps reads done; arena becomes Red
  if (kp2) {
    char* rs = arena + qh * 8192;
#pragma unroll
    for (int dt = 0; dt < 4; ++dt)
#pragma unroll
      for (int qs = 0; qs < 2; ++qs)
        *(f32x4*)(rs + (dt * 2 + qs) * 1024 + epoff) = O[dt][qs];
    if (quad == 0) {
#pragma unroll
      for (int qs = 0; qs < 2; ++qs) Red2[qh][qs][l15] = lsum[qs];
    }
  }
  __syncthreads();
  if (!kp2) {
    const char* rs = arena + qh * 8192;
#pragma unroll
    for (int dt = 0; dt < 4; ++dt)
#pragma unroll
      for (int qs = 0; qs < 2; ++qs)
        O[dt][qs] += *(const f32x4*)(rs + (dt * 2 + qs) * 1024 + epoff);
    unsigned short* yr =
        y + (size_t)(b * TT + qt * 64 + qh * 32 + l15) * CC + h * DD + quad * 4;
#pragma unroll
    for (int qs = 0; qs < 2; ++qs) {
      const float inv = 1.0f / (lsum[qs] + Red2[qh][qs][l15]);
#pragma unroll
      for (int dt = 0; dt < 4; ++dt) {
        bf16x4 o = {(short)f2bf(O[dt][qs][0] * inv),
                    (short)f2bf(O[dt][qs][1] * inv),
                    (short)f2bf(O[dt][qs][2] * inv),
                    (short)f2bf(O[dt][qs][3] * inv)};
        *(bf16x4*)(yr + (size_t)qs * 16 * CC + dt * 16) = o;
      }
    }
  }
}

// ---------------------------------------------------------------------------
extern "C" void kernel_launch(void* const* d_in, const int* in_sizes, int n_in,
                              void* d_out, int out_size, void* d_ws,
                              size_t ws_size, hipStream_t stream) {
  const float* x      = (const float*)d_in[0];
  const float* w_attn = (const float*)d_in[1];
  const float* w_proj = (const float*)d_in[2];
  float* out = (float*)d_out;

  unsigned short* xb   = (unsigned short*)d_ws;
  unsigned short* wat  = xb + (size_t)4096 * 1024;
  unsigned short* wpt  = wat + (size_t)3072 * 1024;
  unsigned short* qkvb = wpt + (size_t)1024 * 1024;
  unsigned short* vt   = qkvb + (size_t)4096 * 3072;
  unsigned short* yb   = vt + (size_t)BB * HH * DD * TT;

  dim3 blk(256);

  prep<<<2048, blk, 0, stream>>>(x, w_attn, w_proj, xb, wat, wpt);

  gemm_qkv<<<dim3(C3 / 128, (BB * TT) / 128), blk, 0, stream>>>(
      xb, wat, qkvb, vt);

  attn_mfma<<<dim3(1024, 1, 1), blk, 0, stream>>>(qkvb, vt, yb);

  gemm_out<<<dim3(CC / 128, (BB * TT) / 64), blk, 0, stream>>>(yb, wpt, out);
}

// Round 5
// 170.796 us; speedup vs baseline: 1.1597x; 1.1597x over previous
//
#include <hip/hip_runtime.h>
#include <hip/hip_bf16.h>
#include <math.h>

// Problem constants: B=2, T=2048, C=1024, H=16, D=64
#define BB 2
#define TT 2048
#define HH 16
#define DD 64
#define CC 1024
#define C3 3072

typedef __attribute__((ext_vector_type(8))) short bf16x8;
typedef __attribute__((ext_vector_type(4))) short bf16x4;
typedef __attribute__((ext_vector_type(4))) float f32x4;
typedef __attribute__((ext_vector_type(2))) unsigned int u32x2;

// round-to-nearest-even fp32 -> bf16 bits
__device__ __forceinline__ unsigned short f2bf(float f) {
  union { float f; unsigned u; } v; v.f = f;
  unsigned r = v.u + 0x7fffu + ((v.u >> 16) & 1u);
  return (unsigned short)(r >> 16);
}
// packed 2x fp32 -> bf16x2 (v_cvt_pk_bf16_f32 on gfx950), RNE
__device__ __forceinline__ unsigned pack2bf(float a, float b) {
  __hip_bfloat162 h = __float22bfloat162_rn(make_float2(a, b));
  union { __hip_bfloat162 h; unsigned u; } cv; cv.h = h;
  return cv.u;
}

// async global->LDS 16B copy (dest = wave-uniform base + lane*16)
__device__ __forceinline__ void async_cp16(const void* g, void* l) {
  __builtin_amdgcn_global_load_lds(
      (const __attribute__((address_space(1))) void*)g,
      (__attribute__((address_space(3))) void*)l, 16, 0, 0);
}

// ---------------------------------------------------------------------------
// prep: one launch does x->bf16 cvt + both weight transposes.
// ---------------------------------------------------------------------------
__global__ __launch_bounds__(256)
void prep(const float* __restrict__ x, const float* __restrict__ w_attn,
          const float* __restrict__ w_proj, unsigned short* __restrict__ xb,
          unsigned short* __restrict__ wat, unsigned short* __restrict__ wpt) {
  __shared__ __align__(16) float Ts[64][68];
  const int bx = blockIdx.x, tid = threadIdx.x;
  if (bx < 1024) {
    int i = bx * 256 + tid;
#pragma unroll
    for (int it = 0; it < 4; ++it, i += 262144) {
      const float4 v = ((const float4*)x)[i];
      bf16x4 o = {(short)f2bf(v.x), (short)f2bf(v.y),
                  (short)f2bf(v.z), (short)f2bf(v.w)};
      ((bf16x4*)xb)[i] = o;
    }
    return;
  }
  const float* W;
  unsigned short* WT;
  int Nd, bound, n0, k0;
  float s;
  if (bx < 1792) {
    const int bid = bx - 1024;
    W = w_attn; WT = wat; Nd = 3072; bound = 1024; s = 0.18033688f;  // 0.125*log2e
    n0 = (bid % 48) * 64; k0 = (bid / 48) * 64;
  } else {
    const int bid = bx - 1792;
    W = w_proj; WT = wpt; Nd = 1024; bound = 0; s = 1.0f;
    n0 = (bid % 16) * 64; k0 = (bid / 16) * 64;
  }
  const int rl = tid >> 4, c4 = tid & 15;
#pragma unroll
  for (int it = 0; it < 4; ++it) {
    const int r = it * 16 + rl;
    *(float4*)&Ts[r][c4 * 4] =
        *(const float4*)(W + (size_t)(k0 + r) * Nd + n0 + c4 * 4);
  }
  __syncthreads();
#pragma unroll
  for (int it = 0; it < 4; ++it) {
    const int n = it * 16 + rl;
    const float sc = (n0 + n < bound) ? s : 1.0f;
    bf16x4 o = {(short)f2bf(Ts[c4 * 4 + 0][n] * sc),
                (short)f2bf(Ts[c4 * 4 + 1][n] * sc),
                (short)f2bf(Ts[c4 * 4 + 2][n] * sc),
                (short)f2bf(Ts[c4 * 4 + 3][n] * sc)};
    *(bf16x4*)(WT + (size_t)(n0 + n) * CC + k0 + c4 * 4) = o;
  }
}

// ---------------------------------------------------------------------------
// gemm_qkv: qkv = xb(4096x1024) @ wat(3072x1024)^T.  Tile 128x128, BK=32,
// dbuf LDS (32 KB), grid 24x32 = 768 blocks = 3 blocks/CU.
// bf16 out; cols>=2048 (V) written transposed into vt[(b*16+h)*64+d][t].
// ---------------------------------------------------------------------------
__global__ __launch_bounds__(256, 3)
void gemm_qkv(const unsigned short* __restrict__ A,
              const unsigned short* __restrict__ BT,
              unsigned short* __restrict__ Cb,
              unsigned short* __restrict__ Vout) {
  __shared__ __align__(16) unsigned short As[2 * 128 * 32];  // 16 KB
  __shared__ __align__(16) unsigned short Bs[2 * 128 * 32];  // 16 KB

  const int tid = threadIdx.x;
  const int w = tid >> 6, lane = tid & 63;
  const int l15 = lane & 15, quad = lane >> 4;
  const int wm = w >> 1, wn = w & 1;
  const int row0 = blockIdx.y * 128, col0 = blockIdx.x * 128;

  const int ca0 = tid, ca1 = tid + 256;
  const int ra0 = ca0 >> 2, ka0 = ((ca0 & 3) ^ ((ca0 >> 3) & 3)) * 8;
  const int ra1 = ca1 >> 2, ka1 = ((ca1 & 3) ^ ((ca1 >> 3) & 3)) * 8;
  const unsigned short* gA0 = A + (size_t)(row0 + ra0) * CC + ka0;
  const unsigned short* gA1 = A + (size_t)(row0 + ra1) * CC + ka1;
  const unsigned short* gB0 = BT + (size_t)(col0 + ra0) * CC + ka0;
  const unsigned short* gB1 = BT + (size_t)(col0 + ra1) * CC + ka1;
  const int la0 = tid * 16, la1 = tid * 16 + 4096;

  const int fro = l15 * 64 + 16 * (quad ^ ((l15 >> 1) & 3));

  f32x4 acc[4][4];
#pragma unroll
  for (int i = 0; i < 4; ++i)
#pragma unroll
    for (int j = 0; j < 4; ++j) acc[i][j] = (f32x4){0.f, 0.f, 0.f, 0.f};

  async_cp16(gA0, (char*)As + la0);
  async_cp16(gA1, (char*)As + la1);
  async_cp16(gB0, (char*)Bs + la0);
  async_cp16(gB1, (char*)Bs + la1);

  for (int i = 0; i < 32; ++i) {
    const int cur = i & 1;
    __syncthreads();

    if (i + 1 < 32) {
      const int k1 = (i + 1) * 32;
      const int ab = (cur ^ 1) * 8192;
      async_cp16(gA0 + k1, (char*)As + ab + la0);
      async_cp16(gA1 + k1, (char*)As + ab + la1);
      async_cp16(gB0 + k1, (char*)Bs + ab + la0);
      async_cp16(gB1 + k1, (char*)Bs + ab + la1);
    }

    const char* fA = (const char*)As + cur * 8192 + wm * 4096 + fro;
    const char* fB = (const char*)Bs + cur * 8192 + wn * 4096 + fro;

    bf16x8 af[4], bf[4];
#pragma unroll
    for (int mt = 0; mt < 4; ++mt) af[mt] = *(const bf16x8*)(fA + mt * 1024);
#pragma unroll
    for (int nt = 0; nt < 4; ++nt) bf[nt] = *(const bf16x8*)(fB + nt * 1024);
#pragma unroll
    for (int mt = 0; mt < 4; ++mt)
#pragma unroll
      for (int nt = 0; nt < 4; ++nt)
        acc[mt][nt] = __builtin_amdgcn_mfma_f32_16x16x32_bf16(
            af[mt], bf[nt], acc[mt][nt], 0, 0, 0);
  }

  if (col0 >= 2048) {
#pragma unroll
    for (int mt = 0; mt < 4; ++mt) {
      const int rbase = row0 + wm * 64 + mt * 16 + quad * 4;
      const int bq = rbase >> 11, t0 = rbase & 2047;
#pragma unroll
      for (int nt = 0; nt < 4; ++nt) {
        const int d = col0 + wn * 64 + nt * 16 + l15 - 2048;
        bf16x4 o = {(short)f2bf(acc[mt][nt][0]), (short)f2bf(acc[mt][nt][1]),
                    (short)f2bf(acc[mt][nt][2]), (short)f2bf(acc[mt][nt][3])};
        *(bf16x4*)(Vout + (((size_t)(bq << 10) + d) << 11) + t0) = o;
      }
    }
  } else {
#pragma unroll
    for (int mt = 0; mt < 4; ++mt) {
      const int rbase = row0 + wm * 64 + mt * 16 + quad * 4;
#pragma unroll
      for (int r = 0; r < 4; ++r) {
        unsigned short* cr =
            Cb + (size_t)(rbase + r) * C3 + col0 + wn * 64 + l15;
#pragma unroll
        for (int nt = 0; nt < 4; ++nt) cr[nt * 16] = f2bf(acc[mt][nt][r]);
      }
    }
  }
}

// ---------------------------------------------------------------------------
// gemm_out: out(4096x1024 fp32) = yb(4096x1024) @ wpt(1024x1024)^T.
// ---------------------------------------------------------------------------
__global__ __launch_bounds__(256, 2)
void gemm_out(const unsigned short* __restrict__ A,
              const unsigned short* __restrict__ BT,
              float* __restrict__ Cf) {
  __shared__ __align__(16) unsigned short As[2 * 64 * 64];    // 16 KB
  __shared__ __align__(16) unsigned short Bs[2 * 128 * 64];   // 32 KB

  const int tid = threadIdx.x;
  const int w = tid >> 6, lane = tid & 63;
  const int l15 = lane & 15, quad = lane >> 4;
  const int wm = w >> 1, wn = w & 1;
  const int row0 = blockIdx.y * 64, col0 = blockIdx.x * 128;

  const int ca0 = tid, ca1 = tid + 256;
  const int ra0 = ca0 >> 3, ka0 = ((ca0 & 7) ^ ((ca0 >> 3) & 7)) * 8;
  const int ra1 = ca1 >> 3, ka1 = ((ca1 & 7) ^ ((ca1 >> 3) & 7)) * 8;
  const unsigned short* gA0 = A + (size_t)(row0 + ra0) * CC + ka0;
  const unsigned short* gA1 = A + (size_t)(row0 + ra1) * CC + ka1;
  const unsigned short* gB[4];
  int lb[4];
#pragma unroll
  for (int t = 0; t < 4; ++t) {
    const int c = tid + t * 256;
    const int rb = c >> 3, kb = ((c & 7) ^ ((c >> 3) & 7)) * 8;
    gB[t] = BT + (size_t)(col0 + rb) * CC + kb;
    lb[t] = c * 16;
  }
  const int la0 = tid * 16, la1 = tid * 16 + 4096;

  const int fro = l15 * 128 + ((quad ^ (l15 & 7)) << 4);

  f32x4 acc[2][4];
#pragma unroll
  for (int i = 0; i < 2; ++i)
#pragma unroll
    for (int j = 0; j < 4; ++j) acc[i][j] = (f32x4){0.f, 0.f, 0.f, 0.f};

  async_cp16(gA0, (char*)As + la0);
  async_cp16(gA1, (char*)As + la1);
#pragma unroll
  for (int t = 0; t < 4; ++t) async_cp16(gB[t], (char*)Bs + lb[t]);

  for (int i = 0; i < 16; ++i) {
    const int cur = i & 1;
    __syncthreads();

    if (i + 1 < 16) {
      const int k1 = (i + 1) * 64;
      const int ab = (cur ^ 1) * 8192, bb = (cur ^ 1) * 16384;
      async_cp16(gA0 + k1, (char*)As + ab + la0);
      async_cp16(gA1 + k1, (char*)As + ab + la1);
#pragma unroll
      for (int t = 0; t < 4; ++t) async_cp16(gB[t] + k1, (char*)Bs + bb + lb[t]);
    }

    const char* fA = (const char*)As + cur * 8192 + wm * 4096 + fro;
    const char* fB = (const char*)Bs + cur * 16384 + wn * 8192 + fro;

#pragma unroll
    for (int kh = 0; kh < 2; ++kh) {
      const int xo = kh * 64;
      bf16x8 af[2], bf[4];
#pragma unroll
      for (int mt = 0; mt < 2; ++mt)
        af[mt] = *(const bf16x8*)(fA + mt * 2048 + ((fro + xo) & 127) - (fro & 127));
#pragma unroll
      for (int nt = 0; nt < 4; ++nt)
        bf[nt] = *(const bf16x8*)(fB + nt * 2048 + ((fro + xo) & 127) - (fro & 127));
#pragma unroll
      for (int mt = 0; mt < 2; ++mt)
#pragma unroll
        for (int nt = 0; nt < 4; ++nt)
          acc[mt][nt] = __builtin_amdgcn_mfma_f32_16x16x32_bf16(
              af[mt], bf[nt], acc[mt][nt], 0, 0, 0);
    }
  }

#pragma unroll
  for (int mt = 0; mt < 2; ++mt) {
    const int rbase = row0 + wm * 32 + mt * 16 + quad * 4;
#pragma unroll
    for (int r = 0; r < 4; ++r) {
      float* cr = Cf + (size_t)(rbase + r) * CC + col0 + wn * 64 + l15;
#pragma unroll
      for (int nt = 0; nt < 4; ++nt) cr[nt * 16] = acc[mt][nt][r];
    }
  }
}

// ---------------------------------------------------------------------------
// MFMA flash attention, round-16: r0's PROVEN dataflow (LDS-staged K/V,
// transposed S^T=KQ^T, ct-XOR swizzled Ps, fixed-max base-2 softmax) scaled
// to 8 waves / 128-row q-tiles.  Evidence r0-r4: perf tracks VMEM-instr
// density per unit work (r4: 8x density = 1.47x slower at HIGHER occupancy);
// r0's shared staging is the minimum-VMEM dataflow.  Changes vs r0:
//  * 512 threads (8 waves), q-tile 128 rows, wave w owns rows w*16..+15.
//    K/V staged ONCE per 128 q-rows (2x amortization); each wave stages
//    1 KB per tile (2 async_cp16 vs 4).
//  * 512 blocks (2/CU) x 16 waves/CU = 4 waves/SIMD (2x r0's TLP).
//    State ~90 regs -> fits __launch_bounds__(512,4) 128-reg budget.
//  * co-residency balance: qb = m<8 ? m : 23-m (CU's two blocks sum 34
//    tiles); waves 0-3 skip the last half-tile (uniform, barriers kept).
//  * no cross-wave reduction (q-split: wave owns its rows end-to-end).
// ---------------------------------------------------------------------------
__global__ __launch_bounds__(512, 4)
void attn_mfma(const unsigned short* __restrict__ qkvb,
               const unsigned short* __restrict__ vt,
               unsigned short* __restrict__ y) {
  const int n = blockIdx.x;
  const int bh = (n & 7) + 8 * ((n >> 3) & 3);  // 4 bh per XCD -> L2-local K/V
  const int m = n >> 5;
  const int qb = (m < 8) ? m : 23 - m;          // co-resident pair balance
  const int b = bh >> 4, h = bh & 15;
  const int tid = threadIdx.x;
  const int w = tid >> 6;
  const int lane = tid & 63;
  const int l15 = lane & 15, quad = lane >> 4;

  __shared__ __align__(16) char Kb[2 * 8192];
  __shared__ __align__(16) char Vb[2 * 8192];
  __shared__ __align__(16) unsigned short Ps[8 * 16 * 72];  // 18,432 B

  char* psw = (char*)Ps + w * 2304;  // per-wave private P staging
  const int psrow = l15 * 144;

  const int lr = lane >> 3;
  const int lc = lane & 7;
  const int srcoff = ((lc ^ lr) << 4);
  const char* ksrc = (const char*)qkvb + ((size_t)(b * TT) * C3 + 1024 + h * 64) * 2;
  const char* vsrc = (const char*)vt + ((size_t)(b * HH + h) * DD * TT) * 2;

  const int fro = l15 * 128 + ((quad ^ (l15 & 7)) << 4);

  bf16x8 onesf;
#pragma unroll
  for (int jj = 0; jj < 8; ++jj) onesf[jj] = (short)0x3F80;

  const int nt = 2 * qb + 2;                       // 64-key tiles in block
  const int qrow_my = qb * 128 + w * 16 + l15;     // this lane's q row
  const int jlast = (qb * 128 + w * 16 + 15) >> 6; // wave's last active tile

  const unsigned short* qrow =
      qkvb + (size_t)(b * TT + qb * 128 + w * 16 + l15) * C3 + h * DD;
  bf16x8 qf0 = *(const bf16x8*)(qrow + quad * 8);
  bf16x8 qf1 = *(const bf16x8*)(qrow + 32 + quad * 8);

  f32x4 O[4];
#pragma unroll
  for (int dt = 0; dt < 4; ++dt) O[dt] = (f32x4){0.f, 0.f, 0.f, 0.f};
  f32x4 lacc = (f32x4){0.f, 0.f, 0.f, 0.f};

  // prologue: stage tile 0 into buf 0 (each wave: 8 K-rows + 8 V-rows, 1KB)
  async_cp16(ksrc + (size_t)(w * 8 + lr) * (C3 * 2) + srcoff, Kb + w * 1024);
  async_cp16(vsrc + (size_t)(w * 8 + lr) * (TT * 2) + srcoff, Vb + w * 1024);

  for (int j = 0; j < nt; ++j) {
    const int cur = j & 1;
    __syncthreads();  // tile j staged; reads of buf cur^1 done

    if (j + 1 < nt) {
      const int key1 = (j + 1) * 64;
      async_cp16(ksrc + (size_t)(key1 + w * 8 + lr) * (C3 * 2) + srcoff,
                 Kb + (cur ^ 1) * 8192 + w * 1024);
      async_cp16(vsrc + (size_t)(w * 8 + lr) * (TT * 2) + key1 * 2 + srcoff,
                 Vb + (cur ^ 1) * 8192 + w * 1024);
    }

    if (j > jlast) continue;  // fully-masked tail tile: staging+barrier only

    const char* Kc = Kb + cur * 8192;
    const char* Vc = Vb + cur * 8192;

    // ---- S^T = K Q^T - 12 ----
    f32x4 S[4];
#pragma unroll
    for (int ct = 0; ct < 4; ++ct) {
      bf16x8 k0 = *(const bf16x8*)(Kc + ct * 2048 + fro);
      bf16x8 k1 = *(const bf16x8*)(Kc + ct * 2048 + (fro ^ 64));
      f32x4 z = (f32x4){-12.f, -12.f, -12.f, -12.f};
      z = __builtin_amdgcn_mfma_f32_16x16x32_bf16(k0, qf0, z, 0, 0, 0);
      z = __builtin_amdgcn_mfma_f32_16x16x32_bf16(k1, qf1, z, 0, 0, 0);
      S[ct] = z;
    }

    if (j == jlast) {  // causal mask on the wave's diagonal tile
#pragma unroll
      for (int ct = 0; ct < 4; ++ct)
#pragma unroll
        for (int r = 0; r < 4; ++r)
          if (64 * j + 16 * ct + quad * 4 + r > qrow_my) S[ct][r] = -INFINITY;
    }

    // ---- P^T = exp2(S^T); pack -> swizzled Ps ----
#pragma unroll
    for (int ct = 0; ct < 4; ++ct) {
      u32x2 d;
      d[0] = pack2bf(__builtin_amdgcn_exp2f(S[ct][0]),
                     __builtin_amdgcn_exp2f(S[ct][1]));
      d[1] = pack2bf(__builtin_amdgcn_exp2f(S[ct][2]),
                     __builtin_amdgcn_exp2f(S[ct][3]));
      *(u32x2*)(psw + psrow + (((ct + l15) & 3) << 5) + quad * 8) = d;
    }

    bf16x8 pf0, pf1;
    {
      const int c0 = (quad >> 1), c1 = 2 + (quad >> 1);
      pf0 = *(const bf16x8*)(psw + psrow + (((c0 + l15) & 3) << 5) + ((quad & 1) << 4));
      pf1 = *(const bf16x8*)(psw + psrow + (((c1 + l15) & 3) << 5) + ((quad & 1) << 4));
    }

    // ---- l[q] += colsum(P^T); O^T += V^T P^T ----
    lacc = __builtin_amdgcn_mfma_f32_16x16x32_bf16(onesf, pf0, lacc, 0, 0, 0);
    lacc = __builtin_amdgcn_mfma_f32_16x16x32_bf16(onesf, pf1, lacc, 0, 0, 0);
#pragma unroll
    for (int dt = 0; dt < 4; ++dt) {
      bf16x8 v0 = *(const bf16x8*)(Vc + dt * 2048 + fro);
      bf16x8 v1 = *(const bf16x8*)(Vc + dt * 2048 + (fro ^ 64));
      O[dt] = __builtin_amdgcn_mfma_f32_16x16x32_bf16(v0, pf0, O[dt], 0, 0, 0);
      O[dt] = __builtin_amdgcn_mfma_f32_16x16x32_bf16(v1, pf1, O[dt], 0, 0, 0);
    }
  }

  // ---- epilogue: lane holds O^T[d=dt*16+quad*4+r][q=l15]; l in lacc ----
  const float inv = 1.0f / lacc[0];
  unsigned short* yr =
      y + (size_t)(b * TT + qb * 128 + w * 16 + l15) * CC + h * DD + quad * 4;
#pragma unroll
  for (int dt = 0; dt < 4; ++dt) {
    bf16x4 o = {(short)f2bf(O[dt][0] * inv), (short)f2bf(O[dt][1] * inv),
                (short)f2bf(O[dt][2] * inv), (short)f2bf(O[dt][3] * inv)};
    *(bf16x4*)(yr + dt * 16) = o;
  }
}

// ---------------------------------------------------------------------------
extern "C" void kernel_launch(void* const* d_in, const int* in_sizes, int n_in,
                              void* d_out, int out_size, void* d_ws,
                              size_t ws_size, hipStream_t stream) {
  const float* x      = (const float*)d_in[0];
  const float* w_attn = (const float*)d_in[1];
  const float* w_proj = (const float*)d_in[2];
  float* out = (float*)d_out;

  unsigned short* xb   = (unsigned short*)d_ws;
  unsigned short* wat  = xb + (size_t)4096 * 1024;
  unsigned short* wpt  = wat + (size_t)3072 * 1024;
  unsigned short* qkvb = wpt + (size_t)1024 * 1024;
  unsigned short* vt   = qkvb + (size_t)4096 * 3072;
  unsigned short* yb   = vt + (size_t)BB * HH * DD * TT;

  dim3 blk(256);

  prep<<<2048, blk, 0, stream>>>(x, w_attn, w_proj, xb, wat, wpt);

  gemm_qkv<<<dim3(C3 / 128, (BB * TT) / 128), blk, 0, stream>>>(
      xb, wat, qkvb, vt);

  attn_mfma<<<dim3(512, 1, 1), dim3(512), 0, stream>>>(qkvb, vt, yb);

  gemm_out<<<dim3(CC / 128, (BB * TT) / 64), blk, 0, stream>>>(yb, wpt, out);
}